// Round 18
// baseline (274.324 us; speedup 1.0000x reference)
//
#include <hip/hip_runtime.h>
#include <hip/hip_bf16.h>
#include <math.h>

#define NN 4096
#define HD 128
#define NCAND 64
#define NCF 10
#define NSEG 16
#define NEGV (-1000000000.0f)

typedef __attribute__((ext_vector_type(8))) short short8_t;
typedef __attribute__((ext_vector_type(4))) float f32x4_t;

// ---- bf16 helpers ---------------------------------------------------------
__device__ __forceinline__ short f2bf(float f) {
    union { __hip_bfloat16 h; short s; } v;
    v.h = __float2bfloat16(f);
    return v.s;
}
__device__ __forceinline__ float bf2f(short s) {
    union { unsigned u; float f; } v; v.u = ((unsigned)(unsigned short)s) << 16;
    return v.f;
}
__device__ __forceinline__ unsigned pk2(float a, float b) {
    union { __hip_bfloat162 h; unsigned u; } v;
    v.h = __float22bfloat162_rn(make_float2(a, b));
    return v.u;
}

// fast gelu: logistic form  x*sigmoid(1.702x)
__device__ __forceinline__ float gelu_f(float x) {
    float e = __builtin_amdgcn_exp2f(2.455466f * x);
    float r = __builtin_amdgcn_rcpf(e + 1.0f);
    return x - x * r;
}

// ---------------------------------------------------------------------------
// merged prep + GAT-layer-1 input transform (independent work, one launch):
// blocks 0..2047: adjacency bitmask pack
// blocks 2048..2055: candidate-weight bf16 conversions (Wc2b/Wfu k-permuted)
// blocks 2056..2311: gatin layer 1 (K=64): H1 = X@W1^T, s/d scalars, Htb
// ---------------------------------------------------------------------------
__global__ __launch_bounds__(256) void prep_gatin_k(
    const int* __restrict__ adj, const float* __restrict__ Wc1,
    const float* __restrict__ Wc2, const float* __restrict__ Ws1,
    unsigned* __restrict__ adjb, short* __restrict__ Wc1b,
    short* __restrict__ Wc2b, short* __restrict__ Wfu,
    const float* __restrict__ X, const float* __restrict__ W1,
    const float* __restrict__ a_s, const float* __restrict__ a_d,
    float* __restrict__ sdv, short* __restrict__ Htb)
{
    constexpr int K = 64, AS = 68;
    __shared__ float in_s[16*AS];
    __shared__ float H_s[16*132];
    int tid = threadIdx.x;

    if (blockIdx.x < 2048) {
        long g = (long)blockIdx.x * 256 + tid;     // 524288 words
        const int4* p = (const int4*)adj + g * 8;
        unsigned wd = 0;
        #pragma unroll
        for (int e = 0; e < 8; ++e) {
            int4 v = p[e];
            wd |= (unsigned)(v.x != 0) << (e*4 + 0);
            wd |= (unsigned)(v.y != 0) << (e*4 + 1);
            wd |= (unsigned)(v.z != 0) << (e*4 + 2);
            wd |= (unsigned)(v.w != 0) << (e*4 + 3);
        }
        adjb[g] = wd;
        return;
    }
    if (blockIdx.x < 2056) {
        int g = (blockIdx.x - 2048) * 256 + tid;
        const int tot = 8 * 256;
        for (int e = g; e < 128*32; e += tot) {
            int t = e >> 5, k = e & 31;
            Wc1b[e] = (k < NCF) ? f2bf(Wc1[t*NCF + k]) : (short)0;
        }
        for (int e = g; e < 128*128; e += tot) {
            int h = e >> 7, pos = e & 127;
            int n = (pos >> 3) | ((pos & 7) << 4);
            Wc2b[e] = f2bf(Wc2[h*128 + n]);
        }
        for (int e = g; e < 128*256; e += tot) {
            int h = e >> 8, j = e & 255;
            int pos = j & 127;
            int n = (pos >> 3) | ((pos & 7) << 4);
            float v = (j < 128) ? Ws1[h*256 + 128 + n] : Ws1[h*256 + n];
            Wfu[e] = f2bf(v);
        }
        return;
    }

    // ---- gatin layer 1 (K=64, from global X) ------------------------------
    int n0 = (blockIdx.x - 2056) * 16;
    {
        constexpr int NV = 16*K/4;    // float4 count
        for (int idx = tid; idx < NV; idx += 256) {
            int row = idx / (K/4), c4 = idx - row*(K/4);
            *(float4*)&in_s[row*AS + c4*4] = *(const float4*)&X[(long)(n0+row)*K + c4*4];
        }
    }
    __syncthreads();

    int w = tid >> 6, l = tid & 63, l15 = l & 15, qd = l >> 4;
    f32x4_t acc[2];
    acc[0] = (f32x4_t){0.f,0.f,0.f,0.f};
    acc[1] = (f32x4_t){0.f,0.f,0.f,0.f};
    #pragma unroll
    for (int kc = 0; kc < K/32; ++kc) {
        int k0 = kc*32 + qd*8;
        float4 x = *(const float4*)&in_s[l15*AS + k0];
        float4 y = *(const float4*)&in_s[l15*AS + k0 + 4];
        union { short8_t s; unsigned u[4]; } a;
        a.u[0]=pk2(x.x,x.y); a.u[1]=pk2(x.z,x.w);
        a.u[2]=pk2(y.x,y.y); a.u[3]=pk2(y.z,y.w);
        #pragma unroll
        for (int it = 0; it < 2; ++it) {
            int n = (w*2+it)*16 + l15;
            float4 w0 = *(const float4*)&W1[(long)n*K + k0];
            float4 w1 = *(const float4*)&W1[(long)n*K + k0 + 4];
            union { short8_t s; unsigned u[4]; } b;
            b.u[0]=pk2(w0.x,w0.y); b.u[1]=pk2(w0.z,w0.w);
            b.u[2]=pk2(w1.x,w1.y); b.u[3]=pk2(w1.z,w1.w);
            acc[it] = __builtin_amdgcn_mfma_f32_16x16x32_bf16(a.s, b.s, acc[it], 0,0,0);
        }
    }
    #pragma unroll
    for (int it = 0; it < 2; ++it)
        #pragma unroll
        for (int r = 0; r < 4; ++r)
            H_s[(qd*4+r)*132 + (w*2+it)*16 + l15] = acc[it][r];
    __syncthreads();
    {   // s/d dot products
        int row = tid >> 4, sg = tid & 15;
        int h0 = sg*8;
        float4 as0 = *(const float4*)&a_s[h0];
        float4 as1 = *(const float4*)&a_s[h0+4];
        float4 ad0 = *(const float4*)&a_d[h0];
        float4 ad1 = *(const float4*)&a_d[h0+4];
        float hv[8];
        #pragma unroll
        for (int e = 0; e < 8; ++e) hv[e] = H_s[row*132 + h0 + e];
        float sp = hv[0]*as0.x + hv[1]*as0.y + hv[2]*as0.z + hv[3]*as0.w
                 + hv[4]*as1.x + hv[5]*as1.y + hv[6]*as1.z + hv[7]*as1.w;
        float dp = hv[0]*ad0.x + hv[1]*ad0.y + hv[2]*ad0.z + hv[3]*ad0.w
                 + hv[4]*ad1.x + hv[5]*ad1.y + hv[6]*ad1.z + hv[7]*ad1.w;
        sp += __shfl_xor(sp,1); sp += __shfl_xor(sp,2);
        sp += __shfl_xor(sp,4); sp += __shfl_xor(sp,8);
        dp += __shfl_xor(dp,1); dp += __shfl_xor(dp,2);
        dp += __shfl_xor(dp,4); dp += __shfl_xor(dp,8);
        if (sg == 0) { sdv[n0+row] = sp; sdv[NN + n0 + row] = dp; }
    }
    {   // transpose -> Htb bf16
        int h = tid & 127, pr = tid >> 7;
        unsigned u[4];
        #pragma unroll
        for (int c2 = 0; c2 < 4; ++c2)
            u[c2] = pk2(H_s[(pr*8 + 2*c2)*132 + h], H_s[(pr*8 + 2*c2 + 1)*132 + h]);
        *(uint4*)&Htb[(long)h*NN + n0 + pr*8] = make_uint4(u[0],u[1],u[2],u[3]);
    }
}

// ---------------------------------------------------------------------------
// gatin layer 2: rows = relu(sum nump/den), writes G1, then H2 = rows@W2^T,
// s/d scalars + Htb. nump layout [node][seg][H] (streaming).
// ---------------------------------------------------------------------------
template<int K, int IN, int OUT>
__global__ __launch_bounds__(256) void gatin_k3(
    const float* __restrict__ in, const float* __restrict__ Wf,
    const float* __restrict__ nump, const float* __restrict__ denp,
    float* __restrict__ G1, const float* __restrict__ ln_w,
    const float* __restrict__ ln_b,
    const float* __restrict__ a_s, const float* __restrict__ a_d,
    float* __restrict__ sdv, short* __restrict__ Htb,
    const float* __restrict__ bias, float* __restrict__ outq)
{
    constexpr int AS = K + 4;
    __shared__ float in_s[16*AS];
    __shared__ float H_s[16*132];
    int tid = threadIdx.x;
    int n0 = blockIdx.x * 16;

    if (IN == 0) {
        constexpr int NV = 16*K/4;
        for (int idx = tid; idx < NV; idx += 256) {
            int row = idx / (K/4), c4 = idx - row*(K/4);
            *(float4*)&in_s[row*AS + c4*4] = *(const float4*)&in[(long)(n0+row)*K + c4*4];
        }
    } else {
        int row = tid >> 4, c8 = (tid & 15) * 8;
        float v[8];
        #pragma unroll
        for (int i = 0; i < 8; ++i) v[i] = 0.f;
        float den = 0.f;
        const float* npr = nump + (long)(n0 + row)*NSEG*HD + c8;
        const float* dpr = denp + (long)(n0 + row)*NSEG;
        #pragma unroll
        for (int s = 0; s < NSEG; ++s) {
            const float* np = npr + s*HD;
            float4 a0 = *(const float4*)np;
            float4 a1 = *(const float4*)(np + 4);
            v[0]+=a0.x; v[1]+=a0.y; v[2]+=a0.z; v[3]+=a0.w;
            v[4]+=a1.x; v[5]+=a1.y; v[6]+=a1.z; v[7]+=a1.w;
            den += dpr[s];
        }
        float rd = (den > 0.f) ? __builtin_amdgcn_rcpf(den) : 0.f;
        if (den > 0.f) rd = rd * (2.0f - den * rd);   // NR refine
        #pragma unroll
        for (int i = 0; i < 8; ++i) v[i] = fmaxf(v[i]*rd, 0.f);
        if (IN == 1) {
            float4 o0 = make_float4(v[0],v[1],v[2],v[3]);
            float4 o1 = make_float4(v[4],v[5],v[6],v[7]);
            *(float4*)&G1[(long)(n0+row)*HD + c8]     = o0;
            *(float4*)&G1[(long)(n0+row)*HD + c8 + 4] = o1;
        }
        #pragma unroll
        for (int i = 0; i < 8; ++i) in_s[row*AS + c8 + i] = v[i];
    }
    __syncthreads();

    int w = tid >> 6, l = tid & 63, l15 = l & 15, qd = l >> 4;
    f32x4_t acc[2];
    acc[0] = (f32x4_t){0.f,0.f,0.f,0.f};
    acc[1] = (f32x4_t){0.f,0.f,0.f,0.f};
    #pragma unroll
    for (int kc = 0; kc < K/32; ++kc) {
        int k0 = kc*32 + qd*8;
        float4 x = *(const float4*)&in_s[l15*AS + k0];
        float4 y = *(const float4*)&in_s[l15*AS + k0 + 4];
        union { short8_t s; unsigned u[4]; } a;
        a.u[0]=pk2(x.x,x.y); a.u[1]=pk2(x.z,x.w);
        a.u[2]=pk2(y.x,y.y); a.u[3]=pk2(y.z,y.w);
        #pragma unroll
        for (int it = 0; it < 2; ++it) {
            int n = (w*2+it)*16 + l15;
            float4 w0 = *(const float4*)&Wf[(long)n*K + k0];
            float4 w1 = *(const float4*)&Wf[(long)n*K + k0 + 4];
            union { short8_t s; unsigned u[4]; } b;
            b.u[0]=pk2(w0.x,w0.y); b.u[1]=pk2(w0.z,w0.w);
            b.u[2]=pk2(w1.x,w1.y); b.u[3]=pk2(w1.z,w1.w);
            acc[it] = __builtin_amdgcn_mfma_f32_16x16x32_bf16(a.s, b.s, acc[it], 0,0,0);
        }
    }

    #pragma unroll
    for (int it = 0; it < 2; ++it)
        #pragma unroll
        for (int r = 0; r < 4; ++r)
            H_s[(qd*4+r)*132 + (w*2+it)*16 + l15] = acc[it][r];
    __syncthreads();
    {   // s/d dot products
        int row = tid >> 4, sg = tid & 15;
        int h0 = sg*8;
        float4 as0 = *(const float4*)&a_s[h0];
        float4 as1 = *(const float4*)&a_s[h0+4];
        float4 ad0 = *(const float4*)&a_d[h0];
        float4 ad1 = *(const float4*)&a_d[h0+4];
        float hv[8];
        #pragma unroll
        for (int e = 0; e < 8; ++e) hv[e] = H_s[row*132 + h0 + e];
        float sp = hv[0]*as0.x + hv[1]*as0.y + hv[2]*as0.z + hv[3]*as0.w
                 + hv[4]*as1.x + hv[5]*as1.y + hv[6]*as1.z + hv[7]*as1.w;
        float dp = hv[0]*ad0.x + hv[1]*ad0.y + hv[2]*ad0.z + hv[3]*ad0.w
                 + hv[4]*ad1.x + hv[5]*ad1.y + hv[6]*ad1.z + hv[7]*ad1.w;
        sp += __shfl_xor(sp,1); sp += __shfl_xor(sp,2);
        sp += __shfl_xor(sp,4); sp += __shfl_xor(sp,8);
        dp += __shfl_xor(dp,1); dp += __shfl_xor(dp,2);
        dp += __shfl_xor(dp,4); dp += __shfl_xor(dp,8);
        if (sg == 0) { sdv[n0+row] = sp; sdv[NN + n0 + row] = dp; }
    }
    {   // transpose -> Htb bf16
        int h = tid & 127, pr = tid >> 7;
        unsigned u[4];
        #pragma unroll
        for (int c2 = 0; c2 < 4; ++c2)
            u[c2] = pk2(H_s[(pr*8 + 2*c2)*132 + h], H_s[(pr*8 + 2*c2 + 1)*132 + h]);
        *(uint4*)&Htb[(long)h*NN + n0 + pr*8] = make_uint4(u[0],u[1],u[2],u[3]);
    }
}

// ---------------------------------------------------------------------------
// GAT aggregate v5 (EXACT R12 config): single-buffered LDS staging,
// launch_bounds(256,4). nump: [node][seg][H].
// ---------------------------------------------------------------------------
__global__ __launch_bounds__(256, 4) void agg_k5(
    const unsigned* __restrict__ adjb, const float* __restrict__ sdv,
    const short* __restrict__ Htb, float* __restrict__ num_part,
    float* __restrict__ den_part)
{
    __shared__ __align__(16) short Bs[128*72];
    __shared__ float dj_s[256];
    int tid = threadIdx.x;
    int i0 = blockIdx.x * 32;
    int seg = blockIdx.y;
    int w = tid >> 6, l = tid & 63, l15 = l & 15, qd = l >> 4;
    int mh = w >> 1, nh = w & 1;
    int arow = i0 + mh*16 + l15;
    float si = sdv[arow];
    const float C1 = 1.44269504f;
    const float C2 = 0.28853901f;

    dj_s[tid] = sdv[NN + seg*256 + tid];

    unsigned wbuf[8];
    {
        const uint4* ap = (const uint4*)&adjb[(long)arow*128 + seg*8];
        uint4 q0 = ap[0], q1 = ap[1];
        wbuf[0]=q0.x; wbuf[1]=q0.y; wbuf[2]=q0.z; wbuf[3]=q0.w;
        wbuf[4]=q1.x; wbuf[5]=q1.y; wbuf[6]=q1.z; wbuf[7]=q1.w;
    }

    int sh = tid >> 1, sj = (tid & 1) * 32;
    const short* srcb = Htb + (long)sh*NN + seg*256 + sj;

    f32x4_t acc[4];
    #pragma unroll
    for (int nt = 0; nt < 4; ++nt) acc[nt] = (f32x4_t){0.f,0.f,0.f,0.f};
    float den = 0.f;

    for (int c4 = 0; c4 < 4; ++c4) {
        __syncthreads();
        {
            const uint4* src = (const uint4*)(srcb + c4*64);
            uint4 v0 = src[0], v1 = src[1], v2 = src[2], v3 = src[3];
            uint4* dst = (uint4*)&Bs[sh*72 + sj];
            dst[0]=v0; dst[1]=v1; dst[2]=v2; dst[3]=v3;
        }
        __syncthreads();
        #pragma unroll
        for (int kc = 0; kc < 2; ++kc) {
            int jl = c4*64 + kc*32 + qd*8;
            float4 da = *(const float4*)&dj_s[jl];
            float4 db = *(const float4*)&dj_s[jl+4];
            unsigned byte_ = (wbuf[c4*2+kc] >> (qd*8)) & 0xffu;
            float dv[8] = {da.x,da.y,da.z,da.w,db.x,db.y,db.z,db.w};
            float v[8];
            #pragma unroll
            for (int e = 0; e < 8; ++e) {
                float z = si + dv[e];
                float k = (z > 0.f) ? C1 : C2;
                float wv = __builtin_amdgcn_exp2f(z * k);
                v[e] = ((byte_ >> e) & 1u) ? wv : 0.f;
                den += v[e];
            }
            union { short8_t s; unsigned u[4]; } a;
            a.u[0]=pk2(v[0],v[1]); a.u[1]=pk2(v[2],v[3]);
            a.u[2]=pk2(v[4],v[5]); a.u[3]=pk2(v[6],v[7]);
            int kb = kc*32 + qd*8;
            #pragma unroll
            for (int nt = 0; nt < 4; ++nt) {
                short8_t b = *(const short8_t*)&Bs[(nh*64 + nt*16 + l15)*72 + kb];
                acc[nt] = __builtin_amdgcn_mfma_f32_16x16x32_bf16(a.s, b, acc[nt], 0,0,0);
            }
        }
    }
    den += __shfl_xor(den, 16); den += __shfl_xor(den, 32);
    if (qd == 0 && nh == 0) den_part[(long)arow*NSEG + seg] = den;
    #pragma unroll
    for (int nt = 0; nt < 4; ++nt)
        #pragma unroll
        for (int r = 0; r < 4; ++r)
            num_part[((long)(i0 + mh*16 + qd*4 + r)*NSEG + seg)*HD
                     + nh*64 + nt*16 + l15] = acc[nt][r];
}

// u-frag helper
__device__ __forceinline__ short8_t mulq2(short8_t c, float4 qa, float4 qb) {
    union { short8_t s; unsigned u[4]; } r;
    r.u[0] = pk2(bf2f(c[0])*qa.x, bf2f(c[1])*qa.y);
    r.u[1] = pk2(bf2f(c[2])*qa.z, bf2f(c[3])*qa.w);
    r.u[2] = pk2(bf2f(c[4])*qb.x, bf2f(c[5])*qb.y);
    r.u[3] = pk2(bf2f(c[6])*qb.z, bf2f(c[7])*qb.w);
    return r.s;
}

// ---------------------------------------------------------------------------
// fused candidate head v9: cand_k8 (N-split, q-on-B, bounds(256,4)) + folded
// layer-2 reduce + LN + q-projection (R9-proven fold; now cheap because
// nump is [node][seg][H] streaming). 5th and final launch.
// ---------------------------------------------------------------------------
__global__ __launch_bounds__(256, 4) void cand_k9(
    const float* __restrict__ cf, const float* __restrict__ am,
    const float* __restrict__ nump, const float* __restrict__ denp,
    const float* __restrict__ G1, const float* __restrict__ ln_w,
    const float* __restrict__ ln_b, const float* __restrict__ Wq,
    const float* __restrict__ bq,
    const short* __restrict__ Wc1b, const short* __restrict__ Wc2b,
    const short* __restrict__ Wfu,
    const float* __restrict__ bc1, const float* __restrict__ bc2,
    const float* __restrict__ bs1, const float* __restrict__ Ws2,
    const float* __restrict__ bs2, float* __restrict__ out)
{
    __shared__ __align__(16) short cand_s[128*136];
    __shared__ float bias_s[128];
    __shared__ __align__(16) float q_s[2][128];
    __shared__ float red_s[128*4];
    __shared__ float noval_s[2];
    __shared__ float hln_s[2][128];
    int tid = threadIdx.x;
    long r0 = (long)blockIdx.x * 128;
    int w = tid >> 6, l = tid & 63, l15 = l & 15, qd = l >> 4;

    // ---- no-valid flag (waves 0,2 own nodes 0,1) --------------------------
    {
        float amv = am[r0 + (long)(w >> 1)*64 + l];
        float tot = amv;
        #pragma unroll
        for (int off = 32; off > 0; off >>= 1) tot += __shfl_xor(tot, off);
        if ((w & 1) == 0 && l == 0) noval_s[w >> 1] = (tot <= 0.f) ? 1.f : 0.f;
    }

    // ---- layer-2 reduce + residual + LN (waves 0,1 -> node w) -------------
    // nump rows are contiguous 8KB streams per node (layout [node][seg][H]).
    if (w < 2) {
        int node = (int)(r0 >> 6) + w;
        float v0 = 0.f, v1 = 0.f, den = 0.f;
        const float* np = nump + (long)node*NSEG*HD;
        const float* dp = denp + (long)node*NSEG;
        #pragma unroll
        for (int s = 0; s < NSEG; ++s) {
            v0 += np[s*HD + l];
            v1 += np[s*HD + l + 64];
            den += dp[s];
        }
        float rd = (den > 0.f) ? __builtin_amdgcn_rcpf(den) : 0.f;
        if (den > 0.f) rd = rd * (2.0f - den * rd);
        v0 = fmaxf(v0*rd, 0.f) + G1[(long)node*HD + l];
        v1 = fmaxf(v1*rd, 0.f) + G1[(long)node*HD + l + 64];
        float sm = v0 + v1, sq = v0*v0 + v1*v1;
        #pragma unroll
        for (int off = 32; off > 0; off >>= 1) {
            sm += __shfl_xor(sm, off);
            sq += __shfl_xor(sq, off);
        }
        float mu  = sm * (1.0f/128.0f);
        float var = sq * (1.0f/128.0f) - mu*mu;
        float nr  = rsqrtf(var + 1e-5f);
        hln_s[w][l]      = (v0 - mu)*nr*ln_w[l]      + ln_b[l];
        hln_s[w][l + 64] = (v1 - mu)*nr*ln_w[l + 64] + ln_b[l + 64];
    }
    __syncthreads();   // B0: hln ready

    // ---- q projection: thread n (<128) computes BOTH nodes (one Wq row
    // read, halves L2 traffic); store permuted positions -------------------
    if (tid < 128) {
        int n = tid;
        const float* wq = Wq + (long)n*HD;
        const float* h0 = hln_s[0];
        const float* h1 = hln_s[1];
        float a0 = bq[n], a1 = a0;
        #pragma unroll 8
        for (int k = 0; k < 128; k += 4) {
            float4 wv = *(const float4*)&wq[k];
            a0 += h0[k]*wv.x + h0[k+1]*wv.y + h0[k+2]*wv.z + h0[k+3]*wv.w;
            a1 += h1[k]*wv.x + h1[k+1]*wv.y + h1[k+2]*wv.z + h1[k+3]*wv.w;
        }
        int pos = ((n & 15) << 3) | (n >> 4);
        q_s[0][pos] = a0;
        q_s[1][pos] = a1;
    }

    // ---- GEMM1 (M-split): A-frags direct from cf; feature-bias ------------
    {
        short8_t fa[2];
        #pragma unroll
        for (int im = 0; im < 2; ++im) {
            long row = r0 + (w*2+im)*16 + l15;
            union { short8_t s; unsigned u[4]; } a;
            float bp = 0.f;
            if (qd == 0) {
                float4 x = *(const float4*)&cf[row*10];
                float4 y = *(const float4*)&cf[row*10+4];
                a.u[0]=pk2(x.x,x.y); a.u[1]=pk2(x.z,x.w);
                a.u[2]=pk2(y.x,y.y); a.u[3]=pk2(y.z,y.w);
                bp = 20.0f*x.x + 1.5f*x.y - 1.5f*x.z + 4.0f*y.x
                   + 1.5f*y.y + 1.2f*y.z + 2.5f*y.w;
            } else if (qd == 1) {
                float2 x = *(const float2*)&cf[row*10+8];
                a.u[0]=pk2(x.x,x.y); a.u[1]=0; a.u[2]=0; a.u[3]=0;
                bp = 1.6f*x.x + 1.2f*x.y;
            } else { a.u[0]=a.u[1]=a.u[2]=a.u[3]=0; }
            bp += __shfl_xor(bp, 16);
            if (qd == 0) bias_s[(w*2+im)*16 + l15] = bp;
            fa[im] = a.s;
        }
        f32x4_t acc1[2][8];
        #pragma unroll
        for (int im = 0; im < 2; ++im)
            #pragma unroll
            for (int nt = 0; nt < 8; ++nt) acc1[im][nt] = (f32x4_t){0.f,0.f,0.f,0.f};
        #pragma unroll
        for (int nt = 0; nt < 8; ++nt) {
            short8_t b = *(const short8_t*)&Wc1b[(nt*16 + l15)*32 + qd*8];
            acc1[0][nt] = __builtin_amdgcn_mfma_f32_16x16x32_bf16(fa[0], b, acc1[0][nt], 0,0,0);
            acc1[1][nt] = __builtin_amdgcn_mfma_f32_16x16x32_bf16(fa[1], b, acc1[1][nt], 0,0,0);
        }
        float bv[8];
        #pragma unroll
        for (int nt = 0; nt < 8; ++nt) bv[nt] = bc1[nt*16 + l15];
        #pragma unroll
        for (int im = 0; im < 2; ++im)
            #pragma unroll
            for (int r = 0; r < 4; ++r) {
                unsigned u[4];
                #pragma unroll
                for (int ph = 0; ph < 4; ++ph) {
                    float g0 = gelu_f(acc1[im][2*ph][r]   + bv[2*ph]);
                    float g1 = gelu_f(acc1[im][2*ph+1][r] + bv[2*ph+1]);
                    u[ph] = pk2(g0, g1);
                }
                int m = (w*2+im)*16 + qd*4 + r;
                *(uint4*)&cand_s[m*136 + l15*8] = make_uint4(u[0],u[1],u[2],u[3]);
            }
    }
    __syncthreads();   // B1: cand1 + bias_s + q_s + noval_s visible

    // ---- GEMM2 (N-split): wave w -> cols w*32..+31, all 128 rows ----------
    f32x4_t acc[8][2];
    #pragma unroll
    for (int mt = 0; mt < 8; ++mt) {
        acc[mt][0] = (f32x4_t){0.f,0.f,0.f,0.f};
        acc[mt][1] = (f32x4_t){0.f,0.f,0.f,0.f};
    }
    #pragma unroll
    for (int kc = 0; kc < 4; ++kc) {
        int kpos = kc*32 + qd*8;
        short8_t a[8];
        #pragma unroll
        for (int mt = 0; mt < 8; ++mt)
            a[mt] = *(const short8_t*)&cand_s[(mt*16 + l15)*136 + kpos];
        short8_t b0 = *(const short8_t*)&Wc2b[((w*2+0)*16 + l15)*128 + kpos];
        short8_t b1 = *(const short8_t*)&Wc2b[((w*2+1)*16 + l15)*128 + kpos];
        #pragma unroll
        for (int mt = 0; mt < 8; ++mt) {
            acc[mt][0] = __builtin_amdgcn_mfma_f32_16x16x32_bf16(a[mt], b0, acc[mt][0], 0,0,0);
            acc[mt][1] = __builtin_amdgcn_mfma_f32_16x16x32_bf16(a[mt], b1, acc[mt][1], 0,0,0);
        }
    }
    __syncthreads();   // B2: all cand1 reads complete before rewrite

    // write cand2: wave w owns permuted positions l15*8 + 2w, +1 (pair)
    {
        float bv0 = bc2[w*32 + l15];
        float bv1 = bc2[w*32 + 16 + l15];
        #pragma unroll
        for (int mt = 0; mt < 8; ++mt)
            #pragma unroll
            for (int r = 0; r < 4; ++r) {
                float g0 = gelu_f(acc[mt][0][r] + bv0);
                float g1 = gelu_f(acc[mt][1][r] + bv1);
                int m = mt*16 + qd*4 + r;
                *(unsigned*)&cand_s[m*136 + l15*8 + w*2] = pk2(g0, g1);
            }
    }
    __syncthreads();   // B3: cand2 visible

    // ---- GEMM3 (N-split, K=256 folded; q applied to B-frags) --------------
    #pragma unroll
    for (int mt = 0; mt < 8; ++mt) {
        acc[mt][0] = (f32x4_t){0.f,0.f,0.f,0.f};
        acc[mt][1] = (f32x4_t){0.f,0.f,0.f,0.f};
    }
    #pragma unroll
    for (int kc = 0; kc < 4; ++kc) {
        int kpos = kc*32 + qd*8;
        short8_t a[8];
        #pragma unroll
        for (int mt = 0; mt < 8; ++mt)
            a[mt] = *(const short8_t*)&cand_s[(mt*16 + l15)*136 + kpos];
        short8_t b00 = *(const short8_t*)&Wfu[((w*2+0)*16 + l15)*256 + kpos];
        short8_t b10 = *(const short8_t*)&Wfu[((w*2+1)*16 + l15)*256 + kpos];
        short8_t b01 = *(const short8_t*)&Wfu[((w*2+0)*16 + l15)*256 + 128 + kpos];
        short8_t b11 = *(const short8_t*)&Wfu[((w*2+1)*16 + l15)*256 + 128 + kpos];
        float4 qa0 = *(const float4*)&q_s[0][kpos];
        float4 qb0 = *(const float4*)&q_s[0][kpos+4];
        float4 qa1 = *(const float4*)&q_s[1][kpos];
        float4 qb1 = *(const float4*)&q_s[1][kpos+4];
        short8_t b01q0 = mulq2(b01, qa0, qb0);
        short8_t b11q0 = mulq2(b11, qa0, qb0);
        short8_t b01q1 = mulq2(b01, qa1, qb1);
        short8_t b11q1 = mulq2(b11, qa1, qb1);
        #pragma unroll
        for (int mt = 0; mt < 8; ++mt) {
            short8_t bq0 = (mt < 4) ? b01q0 : b01q1;
            short8_t bq1 = (mt < 4) ? b11q0 : b11q1;
            acc[mt][0] = __builtin_amdgcn_mfma_f32_16x16x32_bf16(a[mt], b00, acc[mt][0], 0,0,0);
            acc[mt][1] = __builtin_amdgcn_mfma_f32_16x16x32_bf16(a[mt], b10, acc[mt][1], 0,0,0);
            acc[mt][0] = __builtin_amdgcn_mfma_f32_16x16x32_bf16(a[mt], bq0, acc[mt][0], 0,0,0);
            acc[mt][1] = __builtin_amdgcn_mfma_f32_16x16x32_bf16(a[mt], bq1, acc[mt][1], 0,0,0);
        }
    }

    // ---- epilogue: partial logits, cross-wave reduce ----------------------
    {
        float bs1v0 = bs1[w*32 + l15],      bs1v1 = bs1[w*32 + 16 + l15];
        float ws2v0 = Ws2[w*32 + l15],      ws2v1 = Ws2[w*32 + 16 + l15];
        #pragma unroll
        for (int mt = 0; mt < 8; ++mt)
            #pragma unroll
            for (int r = 0; r < 4; ++r) {
                float p = gelu_f(acc[mt][0][r] + bs1v0) * ws2v0
                        + gelu_f(acc[mt][1][r] + bs1v1) * ws2v1;
                p += __shfl_xor(p,1); p += __shfl_xor(p,2);
                p += __shfl_xor(p,4); p += __shfl_xor(p,8);
                if (l15 == 0)
                    red_s[(mt*16 + qd*4 + r)*4 + w] = p;
            }
    }
    __syncthreads();   // B4

    if (tid < 128) {
        int m = tid;
        float lg = red_s[m*4] + red_s[m*4+1] + red_s[m*4+2] + red_s[m*4+3]
                 + bs2[0] + bias_s[m];
        float mk = am[r0 + m];
        if ((m & 63) == 0 && noval_s[m >> 6] > 0.f) mk = 1.0f;
        out[r0 + m] = (mk > 0.f) ? lg : NEGV;
    }
}

// ---------------------------------------------------------------------------
extern "C" void kernel_launch(void* const* d_in, const int* in_sizes, int n_in,
                              void* d_out, int out_size, void* d_ws, size_t ws_size,
                              hipStream_t stream)
{
    const float* X   = (const float*)d_in[0];
    const float* CF  = (const float*)d_in[1];
    const int*   ADJ = (const int*)d_in[2];
    const float* AM  = (const float*)d_in[3];
    const float* W1  = (const float*)d_in[4];
    const float* A1S = (const float*)d_in[5];
    const float* A1D = (const float*)d_in[6];
    const float* W2  = (const float*)d_in[7];
    const float* A2S = (const float*)d_in[8];
    const float* A2D = (const float*)d_in[9];
    const float* LNW = (const float*)d_in[10];
    const float* LNB = (const float*)d_in[11];
    const float* WC1 = (const float*)d_in[12];
    const float* BC1 = (const float*)d_in[13];
    const float* WC2 = (const float*)d_in[14];
    const float* BC2 = (const float*)d_in[15];
    const float* WQ  = (const float*)d_in[16];
    const float* BQ  = (const float*)d_in[17];
    const float* WS1 = (const float*)d_in[18];
    const float* BS1 = (const float*)d_in[19];
    const float* WS2 = (const float*)d_in[20];
    const float* BS2 = (const float*)d_in[21];
    float* OUT = (float*)d_out;

    float* ws = (float*)d_ws;
    float*    G1   = ws;                               // 524288
    float*    sdv  = ws + 524288;                      // 8192 (s,d)
    float*    denp = ws + 532480;                      // 65536 ([node][seg])
    short*    Htb  = (short*)(ws + 598016);            // 524288 shorts
    unsigned* adjb = (unsigned*)(ws + 860160);         // 524288 words
    short*    Wc1b = (short*)(ws + 1384448);           // 4096 shorts
    short*    Wc2b = (short*)(ws + 1386496);           // 16384 shorts
    short*    Wfu  = (short*)(ws + 1394688);           // 32768 shorts
    float*    nump = ws + 1411072;                     // 8388608 ([node][seg][H])

    // launch 1: prep (pack + weight conv) + GAT layer-1 input transform
    prep_gatin_k<<<2312, 256, 0, stream>>>(ADJ, WC1, WC2, WS1,
                                           adjb, Wc1b, Wc2b, Wfu,
                                           X, W1, A1S, A1D, sdv, Htb);
    // launch 2: aggregate layer 1
    agg_k5<<<dim3(128, NSEG), 256, 0, stream>>>(adjb, sdv, Htb, nump, denp);
    // launch 3: layer-1 reduce + layer-2 input transform
    gatin_k3<128, 1, 0><<<256, 256, 0, stream>>>(
        nullptr, W2, nump, denp, G1, nullptr, nullptr,
        A2S, A2D, sdv, Htb, nullptr, nullptr);
    // launch 4: aggregate layer 2
    agg_k5<<<dim3(128, NSEG), 256, 0, stream>>>(adjb, sdv, Htb, nump, denp);
    // launch 5: candidate head (absorbs layer-2 reduce + LN + q-projection)
    cand_k9<<<2048, 256, 0, stream>>>(CF, AM, nump, denp, G1, LNW, LNB, WQ, BQ,
                                      Wc1b, Wc2b, Wfu, BC1, BC2, BS1, WS2, BS2,
                                      OUT);
}

// Round 19
// 264.226 us; speedup vs baseline: 1.0382x; 1.0382x over previous
//
#include <hip/hip_runtime.h>
#include <hip/hip_bf16.h>
#include <math.h>

#define NN 4096
#define HD 128
#define NCAND 64
#define NCF 10
#define NSEG 16
#define NEGV (-1000000000.0f)

typedef __attribute__((ext_vector_type(8))) short short8_t;
typedef __attribute__((ext_vector_type(4))) float f32x4_t;

// ---- bf16 helpers ---------------------------------------------------------
__device__ __forceinline__ short f2bf(float f) {
    union { __hip_bfloat16 h; short s; } v;
    v.h = __float2bfloat16(f);
    return v.s;
}
__device__ __forceinline__ float bf2f(short s) {
    union { unsigned u; float f; } v; v.u = ((unsigned)(unsigned short)s) << 16;
    return v.f;
}
__device__ __forceinline__ unsigned pk2(float a, float b) {
    union { __hip_bfloat162 h; unsigned u; } v;
    v.h = __float22bfloat162_rn(make_float2(a, b));
    return v.u;
}

// fast gelu: logistic form  x*sigmoid(1.702x)
__device__ __forceinline__ float gelu_f(float x) {
    float e = __builtin_amdgcn_exp2f(2.455466f * x);
    float r = __builtin_amdgcn_rcpf(e + 1.0f);
    return x - x * r;
}

// ---------------------------------------------------------------------------
// merged prep + GAT-layer-1 input transform (R18-verified):
// blocks 0..2047: adjacency bitmask pack
// blocks 2048..2055: candidate-weight bf16 conversions (Wc2b/Wfu k-permuted)
// blocks 2056..2311: gatin layer 1 (K=64): H1 = X@W1^T, s/d scalars, Htb
// ---------------------------------------------------------------------------
__global__ __launch_bounds__(256) void prep_gatin_k(
    const int* __restrict__ adj, const float* __restrict__ Wc1,
    const float* __restrict__ Wc2, const float* __restrict__ Ws1,
    unsigned* __restrict__ adjb, short* __restrict__ Wc1b,
    short* __restrict__ Wc2b, short* __restrict__ Wfu,
    const float* __restrict__ X, const float* __restrict__ W1,
    const float* __restrict__ a_s, const float* __restrict__ a_d,
    float* __restrict__ sdv, short* __restrict__ Htb)
{
    constexpr int K = 64, AS = 68;
    __shared__ float in_s[16*AS];
    __shared__ float H_s[16*132];
    int tid = threadIdx.x;

    if (blockIdx.x < 2048) {
        long g = (long)blockIdx.x * 256 + tid;     // 524288 words
        const int4* p = (const int4*)adj + g * 8;
        unsigned wd = 0;
        #pragma unroll
        for (int e = 0; e < 8; ++e) {
            int4 v = p[e];
            wd |= (unsigned)(v.x != 0) << (e*4 + 0);
            wd |= (unsigned)(v.y != 0) << (e*4 + 1);
            wd |= (unsigned)(v.z != 0) << (e*4 + 2);
            wd |= (unsigned)(v.w != 0) << (e*4 + 3);
        }
        adjb[g] = wd;
        return;
    }
    if (blockIdx.x < 2056) {
        int g = (blockIdx.x - 2048) * 256 + tid;
        const int tot = 8 * 256;
        for (int e = g; e < 128*32; e += tot) {
            int t = e >> 5, k = e & 31;
            Wc1b[e] = (k < NCF) ? f2bf(Wc1[t*NCF + k]) : (short)0;
        }
        for (int e = g; e < 128*128; e += tot) {
            int h = e >> 7, pos = e & 127;
            int n = (pos >> 3) | ((pos & 7) << 4);
            Wc2b[e] = f2bf(Wc2[h*128 + n]);
        }
        for (int e = g; e < 128*256; e += tot) {
            int h = e >> 8, j = e & 255;
            int pos = j & 127;
            int n = (pos >> 3) | ((pos & 7) << 4);
            float v = (j < 128) ? Ws1[h*256 + 128 + n] : Ws1[h*256 + n];
            Wfu[e] = f2bf(v);
        }
        return;
    }

    // ---- gatin layer 1 (K=64, from global X) ------------------------------
    int n0 = (blockIdx.x - 2056) * 16;
    {
        constexpr int NV = 16*K/4;
        for (int idx = tid; idx < NV; idx += 256) {
            int row = idx / (K/4), c4 = idx - row*(K/4);
            *(float4*)&in_s[row*AS + c4*4] = *(const float4*)&X[(long)(n0+row)*K + c4*4];
        }
    }
    __syncthreads();

    int w = tid >> 6, l = tid & 63, l15 = l & 15, qd = l >> 4;
    f32x4_t acc[2];
    acc[0] = (f32x4_t){0.f,0.f,0.f,0.f};
    acc[1] = (f32x4_t){0.f,0.f,0.f,0.f};
    #pragma unroll
    for (int kc = 0; kc < K/32; ++kc) {
        int k0 = kc*32 + qd*8;
        float4 x = *(const float4*)&in_s[l15*AS + k0];
        float4 y = *(const float4*)&in_s[l15*AS + k0 + 4];
        union { short8_t s; unsigned u[4]; } a;
        a.u[0]=pk2(x.x,x.y); a.u[1]=pk2(x.z,x.w);
        a.u[2]=pk2(y.x,y.y); a.u[3]=pk2(y.z,y.w);
        #pragma unroll
        for (int it = 0; it < 2; ++it) {
            int n = (w*2+it)*16 + l15;
            float4 w0 = *(const float4*)&W1[(long)n*K + k0];
            float4 w1 = *(const float4*)&W1[(long)n*K + k0 + 4];
            union { short8_t s; unsigned u[4]; } b;
            b.u[0]=pk2(w0.x,w0.y); b.u[1]=pk2(w0.z,w0.w);
            b.u[2]=pk2(w1.x,w1.y); b.u[3]=pk2(w1.z,w1.w);
            acc[it] = __builtin_amdgcn_mfma_f32_16x16x32_bf16(a.s, b.s, acc[it], 0,0,0);
        }
    }
    #pragma unroll
    for (int it = 0; it < 2; ++it)
        #pragma unroll
        for (int r = 0; r < 4; ++r)
            H_s[(qd*4+r)*132 + (w*2+it)*16 + l15] = acc[it][r];
    __syncthreads();
    {   // s/d dot products
        int row = tid >> 4, sg = tid & 15;
        int h0 = sg*8;
        float4 as0 = *(const float4*)&a_s[h0];
        float4 as1 = *(const float4*)&a_s[h0+4];
        float4 ad0 = *(const float4*)&a_d[h0];
        float4 ad1 = *(const float4*)&a_d[h0+4];
        float hv[8];
        #pragma unroll
        for (int e = 0; e < 8; ++e) hv[e] = H_s[row*132 + h0 + e];
        float sp = hv[0]*as0.x + hv[1]*as0.y + hv[2]*as0.z + hv[3]*as0.w
                 + hv[4]*as1.x + hv[5]*as1.y + hv[6]*as1.z + hv[7]*as1.w;
        float dp = hv[0]*ad0.x + hv[1]*ad0.y + hv[2]*ad0.z + hv[3]*ad0.w
                 + hv[4]*ad1.x + hv[5]*ad1.y + hv[6]*ad1.z + hv[7]*ad1.w;
        sp += __shfl_xor(sp,1); sp += __shfl_xor(sp,2);
        sp += __shfl_xor(sp,4); sp += __shfl_xor(sp,8);
        dp += __shfl_xor(dp,1); dp += __shfl_xor(dp,2);
        dp += __shfl_xor(dp,4); dp += __shfl_xor(dp,8);
        if (sg == 0) { sdv[n0+row] = sp; sdv[NN + n0 + row] = dp; }
    }
    {   // transpose -> Htb bf16
        int h = tid & 127, pr = tid >> 7;
        unsigned u[4];
        #pragma unroll
        for (int c2 = 0; c2 < 4; ++c2)
            u[c2] = pk2(H_s[(pr*8 + 2*c2)*132 + h], H_s[(pr*8 + 2*c2 + 1)*132 + h]);
        *(uint4*)&Htb[(long)h*NN + n0 + pr*8] = make_uint4(u[0],u[1],u[2],u[3]);
    }
}

// ---------------------------------------------------------------------------
// gatin (R17 exact): 16 rows/block, grid 256. nump layout [node][seg][H].
// IN 1: rows = relu(sum/den), writes G1.  IN 2: LayerNorm(relu+G1).
// OUT 0: s/d + Htb.  OUT 1: H+bias -> outq (q projection).
// ---------------------------------------------------------------------------
template<int K, int IN, int OUT>
__global__ __launch_bounds__(256) void gatin_k3(
    const float* __restrict__ in, const float* __restrict__ Wf,
    const float* __restrict__ nump, const float* __restrict__ denp,
    float* __restrict__ G1, const float* __restrict__ ln_w,
    const float* __restrict__ ln_b,
    const float* __restrict__ a_s, const float* __restrict__ a_d,
    float* __restrict__ sdv, short* __restrict__ Htb,
    const float* __restrict__ bias, float* __restrict__ outq)
{
    constexpr int AS = K + 4;
    __shared__ float in_s[16*AS];
    __shared__ float H_s[16*132];
    int tid = threadIdx.x;
    int n0 = blockIdx.x * 16;

    if (IN == 0) {
        constexpr int NV = 16*K/4;
        for (int idx = tid; idx < NV; idx += 256) {
            int row = idx / (K/4), c4 = idx - row*(K/4);
            *(float4*)&in_s[row*AS + c4*4] = *(const float4*)&in[(long)(n0+row)*K + c4*4];
        }
    } else {
        int row = tid >> 4, c8 = (tid & 15) * 8;
        float v[8];
        #pragma unroll
        for (int i = 0; i < 8; ++i) v[i] = 0.f;
        float den = 0.f;
        const float* npr = nump + (long)(n0 + row)*NSEG*HD + c8;
        const float* dpr = denp + (long)(n0 + row)*NSEG;
        #pragma unroll
        for (int s = 0; s < NSEG; ++s) {
            const float* np = npr + s*HD;
            float4 a0 = *(const float4*)np;
            float4 a1 = *(const float4*)(np + 4);
            v[0]+=a0.x; v[1]+=a0.y; v[2]+=a0.z; v[3]+=a0.w;
            v[4]+=a1.x; v[5]+=a1.y; v[6]+=a1.z; v[7]+=a1.w;
            den += dpr[s];
        }
        float rd = (den > 0.f) ? __builtin_amdgcn_rcpf(den) : 0.f;
        if (den > 0.f) rd = rd * (2.0f - den * rd);   // NR refine
        #pragma unroll
        for (int i = 0; i < 8; ++i) v[i] = fmaxf(v[i]*rd, 0.f);
        if (IN == 1) {
            float4 o0 = make_float4(v[0],v[1],v[2],v[3]);
            float4 o1 = make_float4(v[4],v[5],v[6],v[7]);
            *(float4*)&G1[(long)(n0+row)*HD + c8]     = o0;
            *(float4*)&G1[(long)(n0+row)*HD + c8 + 4] = o1;
        } else {
            const float* gp = G1 + (long)(n0+row)*HD + c8;
            float4 g0 = *(const float4*)gp;
            float4 g1 = *(const float4*)(gp + 4);
            v[0]+=g0.x; v[1]+=g0.y; v[2]+=g0.z; v[3]+=g0.w;
            v[4]+=g1.x; v[5]+=g1.y; v[6]+=g1.z; v[7]+=g1.w;
            float sm = 0.f, sq = 0.f;
            #pragma unroll
            for (int i = 0; i < 8; ++i) { sm += v[i]; sq += v[i]*v[i]; }
            sm += __shfl_xor(sm,1); sq += __shfl_xor(sq,1);
            sm += __shfl_xor(sm,2); sq += __shfl_xor(sq,2);
            sm += __shfl_xor(sm,4); sq += __shfl_xor(sq,4);
            sm += __shfl_xor(sm,8); sq += __shfl_xor(sq,8);
            float mu  = sm * (1.0f/128.0f);
            float var = sq * (1.0f/128.0f) - mu*mu;
            float nr  = rsqrtf(var + 1e-5f);
            float4 lw0 = *(const float4*)&ln_w[c8];
            float4 lw1 = *(const float4*)&ln_w[c8+4];
            float4 lb0 = *(const float4*)&ln_b[c8];
            float4 lb1 = *(const float4*)&ln_b[c8+4];
            v[0]=(v[0]-mu)*nr*lw0.x+lb0.x; v[1]=(v[1]-mu)*nr*lw0.y+lb0.y;
            v[2]=(v[2]-mu)*nr*lw0.z+lb0.z; v[3]=(v[3]-mu)*nr*lw0.w+lb0.w;
            v[4]=(v[4]-mu)*nr*lw1.x+lb1.x; v[5]=(v[5]-mu)*nr*lw1.y+lb1.y;
            v[6]=(v[6]-mu)*nr*lw1.z+lb1.z; v[7]=(v[7]-mu)*nr*lw1.w+lb1.w;
        }
        #pragma unroll
        for (int i = 0; i < 8; ++i) in_s[row*AS + c8 + i] = v[i];
    }
    __syncthreads();

    int w = tid >> 6, l = tid & 63, l15 = l & 15, qd = l >> 4;
    f32x4_t acc[2];
    acc[0] = (f32x4_t){0.f,0.f,0.f,0.f};
    acc[1] = (f32x4_t){0.f,0.f,0.f,0.f};
    #pragma unroll
    for (int kc = 0; kc < K/32; ++kc) {
        int k0 = kc*32 + qd*8;
        float4 x = *(const float4*)&in_s[l15*AS + k0];
        float4 y = *(const float4*)&in_s[l15*AS + k0 + 4];
        union { short8_t s; unsigned u[4]; } a;
        a.u[0]=pk2(x.x,x.y); a.u[1]=pk2(x.z,x.w);
        a.u[2]=pk2(y.x,y.y); a.u[3]=pk2(y.z,y.w);
        #pragma unroll
        for (int it = 0; it < 2; ++it) {
            int n = (w*2+it)*16 + l15;
            float4 w0 = *(const float4*)&Wf[(long)n*K + k0];
            float4 w1 = *(const float4*)&Wf[(long)n*K + k0 + 4];
            union { short8_t s; unsigned u[4]; } b;
            b.u[0]=pk2(w0.x,w0.y); b.u[1]=pk2(w0.z,w0.w);
            b.u[2]=pk2(w1.x,w1.y); b.u[3]=pk2(w1.z,w1.w);
            acc[it] = __builtin_amdgcn_mfma_f32_16x16x32_bf16(a.s, b.s, acc[it], 0,0,0);
        }
    }

    if (OUT == 1) {
        #pragma unroll
        for (int it = 0; it < 2; ++it) {
            int n = (w*2+it)*16 + l15;
            float bv = bias[n];
            #pragma unroll
            for (int r = 0; r < 4; ++r)
                outq[(long)(n0 + qd*4 + r)*HD + n] = acc[it][r] + bv;
        }
        return;
    }

    #pragma unroll
    for (int it = 0; it < 2; ++it)
        #pragma unroll
        for (int r = 0; r < 4; ++r)
            H_s[(qd*4+r)*132 + (w*2+it)*16 + l15] = acc[it][r];
    __syncthreads();
    {   // s/d dot products
        int row = tid >> 4, sg = tid & 15;
        int h0 = sg*8;
        float4 as0 = *(const float4*)&a_s[h0];
        float4 as1 = *(const float4*)&a_s[h0+4];
        float4 ad0 = *(const float4*)&a_d[h0];
        float4 ad1 = *(const float4*)&a_d[h0+4];
        float hv[8];
        #pragma unroll
        for (int e = 0; e < 8; ++e) hv[e] = H_s[row*132 + h0 + e];
        float sp = hv[0]*as0.x + hv[1]*as0.y + hv[2]*as0.z + hv[3]*as0.w
                 + hv[4]*as1.x + hv[5]*as1.y + hv[6]*as1.z + hv[7]*as1.w;
        float dp = hv[0]*ad0.x + hv[1]*ad0.y + hv[2]*ad0.z + hv[3]*ad0.w
                 + hv[4]*ad1.x + hv[5]*ad1.y + hv[6]*ad1.z + hv[7]*ad1.w;
        sp += __shfl_xor(sp,1); sp += __shfl_xor(sp,2);
        sp += __shfl_xor(sp,4); sp += __shfl_xor(sp,8);
        dp += __shfl_xor(dp,1); dp += __shfl_xor(dp,2);
        dp += __shfl_xor(dp,4); dp += __shfl_xor(dp,8);
        if (sg == 0) { sdv[n0+row] = sp; sdv[NN + n0 + row] = dp; }
    }
    {   // transpose -> Htb bf16
        int h = tid & 127, pr = tid >> 7;
        unsigned u[4];
        #pragma unroll
        for (int c2 = 0; c2 < 4; ++c2)
            u[c2] = pk2(H_s[(pr*8 + 2*c2)*132 + h], H_s[(pr*8 + 2*c2 + 1)*132 + h]);
        *(uint4*)&Htb[(long)h*NN + n0 + pr*8] = make_uint4(u[0],u[1],u[2],u[3]);
    }
}

// ---------------------------------------------------------------------------
// GAT aggregate v5 (R12/R17 exact): single-buffered LDS staging,
// launch_bounds(256,4). nump: [node][seg][H].
// ---------------------------------------------------------------------------
__global__ __launch_bounds__(256, 4) void agg_k5(
    const unsigned* __restrict__ adjb, const float* __restrict__ sdv,
    const short* __restrict__ Htb, float* __restrict__ num_part,
    float* __restrict__ den_part)
{
    __shared__ __align__(16) short Bs[128*72];
    __shared__ float dj_s[256];
    int tid = threadIdx.x;
    int i0 = blockIdx.x * 32;
    int seg = blockIdx.y;
    int w = tid >> 6, l = tid & 63, l15 = l & 15, qd = l >> 4;
    int mh = w >> 1, nh = w & 1;
    int arow = i0 + mh*16 + l15;
    float si = sdv[arow];
    const float C1 = 1.44269504f;
    const float C2 = 0.28853901f;

    dj_s[tid] = sdv[NN + seg*256 + tid];

    unsigned wbuf[8];
    {
        const uint4* ap = (const uint4*)&adjb[(long)arow*128 + seg*8];
        uint4 q0 = ap[0], q1 = ap[1];
        wbuf[0]=q0.x; wbuf[1]=q0.y; wbuf[2]=q0.z; wbuf[3]=q0.w;
        wbuf[4]=q1.x; wbuf[5]=q1.y; wbuf[6]=q1.z; wbuf[7]=q1.w;
    }

    int sh = tid >> 1, sj = (tid & 1) * 32;
    const short* srcb = Htb + (long)sh*NN + seg*256 + sj;

    f32x4_t acc[4];
    #pragma unroll
    for (int nt = 0; nt < 4; ++nt) acc[nt] = (f32x4_t){0.f,0.f,0.f,0.f};
    float den = 0.f;

    for (int c4 = 0; c4 < 4; ++c4) {
        __syncthreads();
        {
            const uint4* src = (const uint4*)(srcb + c4*64);
            uint4 v0 = src[0], v1 = src[1], v2 = src[2], v3 = src[3];
            uint4* dst = (uint4*)&Bs[sh*72 + sj];
            dst[0]=v0; dst[1]=v1; dst[2]=v2; dst[3]=v3;
        }
        __syncthreads();
        #pragma unroll
        for (int kc = 0; kc < 2; ++kc) {
            int jl = c4*64 + kc*32 + qd*8;
            float4 da = *(const float4*)&dj_s[jl];
            float4 db = *(const float4*)&dj_s[jl+4];
            unsigned byte_ = (wbuf[c4*2+kc] >> (qd*8)) & 0xffu;
            float dv[8] = {da.x,da.y,da.z,da.w,db.x,db.y,db.z,db.w};
            float v[8];
            #pragma unroll
            for (int e = 0; e < 8; ++e) {
                float z = si + dv[e];
                float k = (z > 0.f) ? C1 : C2;
                float wv = __builtin_amdgcn_exp2f(z * k);
                v[e] = ((byte_ >> e) & 1u) ? wv : 0.f;
                den += v[e];
            }
            union { short8_t s; unsigned u[4]; } a;
            a.u[0]=pk2(v[0],v[1]); a.u[1]=pk2(v[2],v[3]);
            a.u[2]=pk2(v[4],v[5]); a.u[3]=pk2(v[6],v[7]);
            int kb = kc*32 + qd*8;
            #pragma unroll
            for (int nt = 0; nt < 4; ++nt) {
                short8_t b = *(const short8_t*)&Bs[(nh*64 + nt*16 + l15)*72 + kb];
                acc[nt] = __builtin_amdgcn_mfma_f32_16x16x32_bf16(a.s, b, acc[nt], 0,0,0);
            }
        }
    }
    den += __shfl_xor(den, 16); den += __shfl_xor(den, 32);
    if (qd == 0 && nh == 0) den_part[(long)arow*NSEG + seg] = den;
    #pragma unroll
    for (int nt = 0; nt < 4; ++nt)
        #pragma unroll
        for (int r = 0; r < 4; ++r)
            num_part[((long)(i0 + mh*16 + qd*4 + r)*NSEG + seg)*HD
                     + nh*64 + nt*16 + l15] = acc[nt][r];
}

// u-frag helper
__device__ __forceinline__ short8_t mulq2(short8_t c, float4 qa, float4 qb) {
    union { short8_t s; unsigned u[4]; } r;
    r.u[0] = pk2(bf2f(c[0])*qa.x, bf2f(c[1])*qa.y);
    r.u[1] = pk2(bf2f(c[2])*qa.z, bf2f(c[3])*qa.w);
    r.u[2] = pk2(bf2f(c[4])*qb.x, bf2f(c[5])*qb.y);
    r.u[3] = pk2(bf2f(c[6])*qb.z, bf2f(c[7])*qb.w);
    return r.s;
}

// ---------------------------------------------------------------------------
// fused candidate head (R17 exact): N-split GEMM2/3, q on B side, single
// 2048-block launch, bounds(256,4) (lean body, VGPR 64, no spill).
// ---------------------------------------------------------------------------
__global__ __launch_bounds__(256, 4) void cand_k8(
    const float* __restrict__ cf, const float* __restrict__ am,
    const float* __restrict__ Qb,
    const short* __restrict__ Wc1b, const short* __restrict__ Wc2b,
    const short* __restrict__ Wfu,
    const float* __restrict__ bc1, const float* __restrict__ bc2,
    const float* __restrict__ bs1, const float* __restrict__ Ws2,
    const float* __restrict__ bs2, float* __restrict__ out)
{
    __shared__ __align__(16) short cand_s[128*136];
    __shared__ float bias_s[128];
    __shared__ __align__(16) float q_s[2][128];
    __shared__ float red_s[128*4];
    __shared__ float noval_s[2];
    int tid = threadIdx.x;
    long r0 = (long)blockIdx.x * 128;
    int w = tid >> 6, l = tid & 63, l15 = l & 15, qd = l >> 4;

    // ---- no-valid flag (waves 0,2 own nodes 0,1) --------------------------
    {
        float amv = am[r0 + (long)(w >> 1)*64 + l];
        float tot = amv;
        #pragma unroll
        for (int off = 32; off > 0; off >>= 1) tot += __shfl_xor(tot, off);
        if ((w & 1) == 0 && l == 0) noval_s[w >> 1] = (tot <= 0.f) ? 1.f : 0.f;
    }

    // ---- q load (permuted positions) --------------------------------------
    {
        int nd = tid >> 7, n = tid & 127;
        float qv = Qb[((r0 >> 6) + nd)*HD + n];
        int pos = ((n & 15) << 3) | (n >> 4);
        q_s[nd][pos] = qv;
    }

    // ---- GEMM1 (M-split): A-frags direct from cf; feature-bias ------------
    {
        short8_t fa[2];
        #pragma unroll
        for (int im = 0; im < 2; ++im) {
            long row = r0 + (w*2+im)*16 + l15;
            union { short8_t s; unsigned u[4]; } a;
            float bp = 0.f;
            if (qd == 0) {
                float4 x = *(const float4*)&cf[row*10];
                float4 y = *(const float4*)&cf[row*10+4];
                a.u[0]=pk2(x.x,x.y); a.u[1]=pk2(x.z,x.w);
                a.u[2]=pk2(y.x,y.y); a.u[3]=pk2(y.z,y.w);
                bp = 20.0f*x.x + 1.5f*x.y - 1.5f*x.z + 4.0f*y.x
                   + 1.5f*y.y + 1.2f*y.z + 2.5f*y.w;
            } else if (qd == 1) {
                float2 x = *(const float2*)&cf[row*10+8];
                a.u[0]=pk2(x.x,x.y); a.u[1]=0; a.u[2]=0; a.u[3]=0;
                bp = 1.6f*x.x + 1.2f*x.y;
            } else { a.u[0]=a.u[1]=a.u[2]=a.u[3]=0; }
            bp += __shfl_xor(bp, 16);
            if (qd == 0) bias_s[(w*2+im)*16 + l15] = bp;
            fa[im] = a.s;
        }
        f32x4_t acc1[2][8];
        #pragma unroll
        for (int im = 0; im < 2; ++im)
            #pragma unroll
            for (int nt = 0; nt < 8; ++nt) acc1[im][nt] = (f32x4_t){0.f,0.f,0.f,0.f};
        #pragma unroll
        for (int nt = 0; nt < 8; ++nt) {
            short8_t b = *(const short8_t*)&Wc1b[(nt*16 + l15)*32 + qd*8];
            acc1[0][nt] = __builtin_amdgcn_mfma_f32_16x16x32_bf16(fa[0], b, acc1[0][nt], 0,0,0);
            acc1[1][nt] = __builtin_amdgcn_mfma_f32_16x16x32_bf16(fa[1], b, acc1[1][nt], 0,0,0);
        }
        float bv[8];
        #pragma unroll
        for (int nt = 0; nt < 8; ++nt) bv[nt] = bc1[nt*16 + l15];
        #pragma unroll
        for (int im = 0; im < 2; ++im)
            #pragma unroll
            for (int r = 0; r < 4; ++r) {
                unsigned u[4];
                #pragma unroll
                for (int ph = 0; ph < 4; ++ph) {
                    float g0 = gelu_f(acc1[im][2*ph][r]   + bv[2*ph]);
                    float g1 = gelu_f(acc1[im][2*ph+1][r] + bv[2*ph+1]);
                    u[ph] = pk2(g0, g1);
                }
                int m = (w*2+im)*16 + qd*4 + r;
                *(uint4*)&cand_s[m*136 + l15*8] = make_uint4(u[0],u[1],u[2],u[3]);
            }
    }
    __syncthreads();   // B1: cand1 + bias_s + q_s + noval_s visible

    // ---- GEMM2 (N-split): wave w -> cols w*32..+31, all 128 rows ----------
    f32x4_t acc[8][2];
    #pragma unroll
    for (int mt = 0; mt < 8; ++mt) {
        acc[mt][0] = (f32x4_t){0.f,0.f,0.f,0.f};
        acc[mt][1] = (f32x4_t){0.f,0.f,0.f,0.f};
    }
    #pragma unroll
    for (int kc = 0; kc < 4; ++kc) {
        int kpos = kc*32 + qd*8;
        short8_t a[8];
        #pragma unroll
        for (int mt = 0; mt < 8; ++mt)
            a[mt] = *(const short8_t*)&cand_s[(mt*16 + l15)*136 + kpos];
        short8_t b0 = *(const short8_t*)&Wc2b[((w*2+0)*16 + l15)*128 + kpos];
        short8_t b1 = *(const short8_t*)&Wc2b[((w*2+1)*16 + l15)*128 + kpos];
        #pragma unroll
        for (int mt = 0; mt < 8; ++mt) {
            acc[mt][0] = __builtin_amdgcn_mfma_f32_16x16x32_bf16(a[mt], b0, acc[mt][0], 0,0,0);
            acc[mt][1] = __builtin_amdgcn_mfma_f32_16x16x32_bf16(a[mt], b1, acc[mt][1], 0,0,0);
        }
    }
    __syncthreads();   // B2: all cand1 reads complete before rewrite

    // write cand2: wave w owns permuted positions l15*8 + 2w, +1 (pair)
    {
        float bv0 = bc2[w*32 + l15];
        float bv1 = bc2[w*32 + 16 + l15];
        #pragma unroll
        for (int mt = 0; mt < 8; ++mt)
            #pragma unroll
            for (int r = 0; r < 4; ++r) {
                float g0 = gelu_f(acc[mt][0][r] + bv0);
                float g1 = gelu_f(acc[mt][1][r] + bv1);
                int m = mt*16 + qd*4 + r;
                *(unsigned*)&cand_s[m*136 + l15*8 + w*2] = pk2(g0, g1);
            }
    }
    __syncthreads();   // B3: cand2 visible

    // ---- GEMM3 (N-split, K=256 folded; q applied to B-frags) --------------
    #pragma unroll
    for (int mt = 0; mt < 8; ++mt) {
        acc[mt][0] = (f32x4_t){0.f,0.f,0.f,0.f};
        acc[mt][1] = (f32x4_t){0.f,0.f,0.f,0.f};
    }
    #pragma unroll
    for (int kc = 0; kc < 4; ++kc) {
        int kpos = kc*32 + qd*8;
        short8_t a[8];
        #pragma unroll
        for (int mt = 0; mt < 8; ++mt)
            a[mt] = *(const short8_t*)&cand_s[(mt*16 + l15)*136 + kpos];
        short8_t b00 = *(const short8_t*)&Wfu[((w*2+0)*16 + l15)*256 + kpos];
        short8_t b10 = *(const short8_t*)&Wfu[((w*2+1)*16 + l15)*256 + kpos];
        short8_t b01 = *(const short8_t*)&Wfu[((w*2+0)*16 + l15)*256 + 128 + kpos];
        short8_t b11 = *(const short8_t*)&Wfu[((w*2+1)*16 + l15)*256 + 128 + kpos];
        float4 qa0 = *(const float4*)&q_s[0][kpos];
        float4 qb0 = *(const float4*)&q_s[0][kpos+4];
        float4 qa1 = *(const float4*)&q_s[1][kpos];
        float4 qb1 = *(const float4*)&q_s[1][kpos+4];
        short8_t b01q0 = mulq2(b01, qa0, qb0);
        short8_t b11q0 = mulq2(b11, qa0, qb0);
        short8_t b01q1 = mulq2(b01, qa1, qb1);
        short8_t b11q1 = mulq2(b11, qa1, qb1);
        #pragma unroll
        for (int mt = 0; mt < 8; ++mt) {
            short8_t bq0 = (mt < 4) ? b01q0 : b01q1;
            short8_t bq1 = (mt < 4) ? b11q0 : b11q1;
            acc[mt][0] = __builtin_amdgcn_mfma_f32_16x16x32_bf16(a[mt], b00, acc[mt][0], 0,0,0);
            acc[mt][1] = __builtin_amdgcn_mfma_f32_16x16x32_bf16(a[mt], b10, acc[mt][1], 0,0,0);
            acc[mt][0] = __builtin_amdgcn_mfma_f32_16x16x32_bf16(a[mt], bq0, acc[mt][0], 0,0,0);
            acc[mt][1] = __builtin_amdgcn_mfma_f32_16x16x32_bf16(a[mt], bq1, acc[mt][1], 0,0,0);
        }
    }

    // ---- epilogue: partial logits, cross-wave reduce ----------------------
    {
        float bs1v0 = bs1[w*32 + l15],      bs1v1 = bs1[w*32 + 16 + l15];
        float ws2v0 = Ws2[w*32 + l15],      ws2v1 = Ws2[w*32 + 16 + l15];
        #pragma unroll
        for (int mt = 0; mt < 8; ++mt)
            #pragma unroll
            for (int r = 0; r < 4; ++r) {
                float p = gelu_f(acc[mt][0][r] + bs1v0) * ws2v0
                        + gelu_f(acc[mt][1][r] + bs1v1) * ws2v1;
                p += __shfl_xor(p,1); p += __shfl_xor(p,2);
                p += __shfl_xor(p,4); p += __shfl_xor(p,8);
                if (l15 == 0)
                    red_s[(mt*16 + qd*4 + r)*4 + w] = p;
            }
    }
    __syncthreads();   // B4

    if (tid < 128) {
        int m = tid;
        float lg = red_s[m*4] + red_s[m*4+1] + red_s[m*4+2] + red_s[m*4+3]
                 + bs2[0] + bias_s[m];
        float mk = am[r0 + m];
        if ((m & 63) == 0 && noval_s[m >> 6] > 0.f) mk = 1.0f;
        out[r0 + m] = (mk > 0.f) ? lg : NEGV;
    }
}

// ---------------------------------------------------------------------------
extern "C" void kernel_launch(void* const* d_in, const int* in_sizes, int n_in,
                              void* d_out, int out_size, void* d_ws, size_t ws_size,
                              hipStream_t stream)
{
    const float* X   = (const float*)d_in[0];
    const float* CF  = (const float*)d_in[1];
    const int*   ADJ = (const int*)d_in[2];
    const float* AM  = (const float*)d_in[3];
    const float* W1  = (const float*)d_in[4];
    const float* A1S = (const float*)d_in[5];
    const float* A1D = (const float*)d_in[6];
    const float* W2  = (const float*)d_in[7];
    const float* A2S = (const float*)d_in[8];
    const float* A2D = (const float*)d_in[9];
    const float* LNW = (const float*)d_in[10];
    const float* LNB = (const float*)d_in[11];
    const float* WC1 = (const float*)d_in[12];
    const float* BC1 = (const float*)d_in[13];
    const float* WC2 = (const float*)d_in[14];
    const float* BC2 = (const float*)d_in[15];
    const float* WQ  = (const float*)d_in[16];
    const float* BQ  = (const float*)d_in[17];
    const float* WS1 = (const float*)d_in[18];
    const float* BS1 = (const float*)d_in[19];
    const float* WS2 = (const float*)d_in[20];
    const float* BS2 = (const float*)d_in[21];
    float* OUT = (float*)d_out;

    float* ws = (float*)d_ws;
    float*    G1   = ws;                               // 524288
    float*    Qb   = ws + 524288;                      // 524288
    float*    sdv  = ws + 1048576;                     // 8192 (s,d)
    float*    denp = ws + 1056768;                     // 65536 ([node][seg])
    short*    Htb  = (short*)(ws + 1122304);           // 524288 shorts
    unsigned* adjb = (unsigned*)(ws + 1384448);        // 524288 words
    short*    Wc1b = (short*)(ws + 1908736);           // 4096 shorts
    short*    Wc2b = (short*)(ws + 1910784);           // 16384 shorts
    short*    Wfu  = (short*)(ws + 1918976);           // 32768 shorts
    float*    nump = ws + 1935360;                     // 8388608 ([node][seg][H])

    // launch 1: prep (pack + weight conv) + GAT layer-1 input transform
    prep_gatin_k<<<2312, 256, 0, stream>>>(ADJ, WC1, WC2, WS1,
                                           adjb, Wc1b, Wc2b, Wfu,
                                           X, W1, A1S, A1D, sdv, Htb);
    // launch 2: aggregate layer 1
    agg_k5<<<dim3(128, NSEG), 256, 0, stream>>>(adjb, sdv, Htb, nump, denp);
    // launch 3: layer-1 reduce + layer-2 input transform
    gatin_k3<128, 1, 0><<<256, 256, 0, stream>>>(
        nullptr, W2, nump, denp, G1, nullptr, nullptr,
        A2S, A2D, sdv, Htb, nullptr, nullptr);
    // launch 4: aggregate layer 2
    agg_k5<<<dim3(128, NSEG), 256, 0, stream>>>(adjb, sdv, Htb, nump, denp);
    // launch 5: layer-2 reduce + residual + LN + q projection
    gatin_k3<128, 2, 1><<<256, 256, 0, stream>>>(
        nullptr, WQ, nump, denp, G1, LNW, LNB,
        nullptr, nullptr, nullptr, nullptr, BQ, Qb);
    // launch 6: fused candidate head
    cand_k8<<<2048, 256, 0, stream>>>(CF, AM, Qb, Wc1b, Wc2b, Wfu,
                                      BC1, BC2, BS1, WS2, BS2, OUT);
}